// Round 9
// baseline (1097.843 us; speedup 1.0000x reference)
//
#include <hip/hip_runtime.h>
#include <stdint.h>

#define HIDDEN 4096
#define M_TOK 8192   // B*S
#define KDIM 4096

typedef __attribute__((ext_vector_type(8))) __bf16 bf16x8;
typedef __attribute__((ext_vector_type(4))) float f32x4;
typedef __attribute__((ext_vector_type(8))) unsigned short u16x8;

#define GAS __attribute__((address_space(1)))
#define LAS __attribute__((address_space(3)))

__device__ __forceinline__ unsigned short f2bf(float f) {
  unsigned int u = __float_as_uint(f);
  u += 0x7FFFu + ((u >> 16) & 1u);
  return (unsigned short)(u >> 16);
}
__device__ __forceinline__ float bf2f(unsigned short b) {
  return __uint_as_float(((unsigned int)b) << 16);
}

// ---------- fused fp32->bf16 conversions + bias pack, one launch ----------
__device__ __forceinline__ void cvt8(const float* __restrict__ in,
                                     unsigned short* __restrict__ out, int i) {
  const f32x4* p = (const f32x4*)in + (size_t)2 * i;
  f32x4 a = p[0], b = p[1];
  u16x8 o;
  o[0] = f2bf(a.x); o[1] = f2bf(a.y); o[2] = f2bf(a.z); o[3] = f2bf(a.w);
  o[4] = f2bf(b.x); o[5] = f2bf(b.y); o[6] = f2bf(b.z); o[7] = f2bf(b.w);
  ((u16x8*)out)[i] = o;
}

__global__ __launch_bounds__(256) void cvt_fused(
    const float* __restrict__ hs, const float* __restrict__ wq,
    const float* __restrict__ wk, const float* __restrict__ wv,
    const float* __restrict__ bq, const float* __restrict__ bk,
    const float* __restrict__ bv,
    unsigned short* __restrict__ hsb, unsigned short* __restrict__ wb,
    float* __restrict__ bias) {
  int b = blockIdx.x;
  int tid = threadIdx.x;
  if (b < 16384) {                      // hs: 33.5M elems
    cvt8(hs, hsb, b * 256 + tid);
  } else if (b < 24576) {               // wq
    cvt8(wq, wb, (b - 16384) * 256 + tid);
  } else if (b < 32768) {               // wk
    cvt8(wk, wb + 16777216, (b - 24576) * 256 + tid);
  } else if (b < 40960) {               // wv
    cvt8(wv, wb + 33554432, (b - 32768) * 256 + tid);
  } else {                              // bias pack
    int i = (b - 40960) * 256 + tid;
    float v = (i < 4096) ? bq[i] : (i < 8192) ? bk[i - 4096] : bv[i - 8192];
    bias[i] = v;
  }
}

// ============================================================================
// 128x256 QKV GEMM, BK=32, 256 thr = 4 waves (1M x 4N), 2 blocks/CU.
// R8 post-mortem (corrected LDS arithmetic): 256^2/1-block is at an LDS-BW
// wall (reads 2304 + writes 512 cyc/K-tile vs MFMA 2483; measured 4128 =
// imperfect overlap). This config keeps the SAME FLOP/LDS-byte ratio (42.7:
// redundancy wN*BM + wM*BN = 1024 vs tile 32768) but with 48 KiB LDS ->
// 2 independent blocks/CU: cross-block overlap saturates the LDS port
// (m114 mechanism; R6 proved saturation works but had ratio 21.3 -> slow).
// Per wave: 128x64 out = acc[8][4] (128 AGPR); av[8]+bv[4] reads = 12 b128
// per K-tile. Swizzle: chunk' = lk ^ (l16&3) on 64-B rows -- structurally
// identical to R3's 0-conflict pattern (8 lanes/16B-slot, distinct rows,
// all 32 banks balanced). Schedule: R6's proven 2-barrier K-tile.
// ============================================================================
#define BAR() __builtin_amdgcn_s_barrier()
#define PRIO(p) __builtin_amdgcn_s_setprio(p)
#define VMC6() asm volatile("s_waitcnt vmcnt(6)" ::: "memory")
#define VMC0() asm volatile("s_waitcnt vmcnt(0)" ::: "memory")
#define LGKM0() do { asm volatile("s_waitcnt lgkmcnt(0)" ::: "memory"); \
  __builtin_amdgcn_sched_barrier(0); } while (0)
#define SB0() __builtin_amdgcn_sched_barrier(0)

__global__ __launch_bounds__(256, 2) void gemm_qkv(
    const unsigned short* __restrict__ A,   // [8192][4096] bf16
    const unsigned short* __restrict__ W,   // [12288][4096] bf16 (wq;wk;wv)
    const float* __restrict__ bias,         // [12288]
    unsigned short* __restrict__ out) {     // [3][8192][4096] bf16
  __shared__ __attribute__((aligned(16))) unsigned short lds[24576];  // 48 KiB

  int tid = threadIdx.x;       // 0..255
  int lane = tid & 63;
  int wn = tid >> 6;           // wave 0..3 -> col strip wn*64
  int l16 = lane & 15;
  int lk = lane >> 4;

  // ---- 2D XCD slab map (grid = 3072 = 8 XCD * 8 tm * 48 tn; 64 co-res/XCD) ----
  int bid = blockIdx.x;
  int xcd = bid & 7;
  int local = bid >> 3;        // 0..383
  int r = local >> 6;          // 0..5 tn-round
  int i = local & 63;          // 0..63 co-resident slot (2/CU * 32 CU)
  int tm = (xcd << 3) + (i >> 3);   // 0..63
  int tn = (r << 3) + (i & 7);      // 0..47
  int m0 = tm << 7, n0 = tn << 8;

  // ---- staging source: pre-swizzled global col (2-bit XOR by row&3) ----
  int rsub = tid >> 2;                                   // 0..63
  int ce = (((tid & 3) ^ (rsub & 3)) << 3);              // col elems, swizzled
  const unsigned short* aSrc = A + (size_t)(m0 + rsub) * KDIM + ce;
  const unsigned short* bSrc = W + (size_t)(n0 + rsub) * KDIM + ce;
  int tid8 = tid * 8;

  // LDS shorts: A[2][128][32] at 0 (4096/buf); B[2][256][32] at 8192 (8192/buf)
#define STAGE(b, kt) do { \
  __builtin_amdgcn_global_load_lds((GAS void*)(aSrc + (kt)*32), \
      (LAS void*)(lds + (b)*4096 + tid8), 16, 0, 0); \
  __builtin_amdgcn_global_load_lds((GAS void*)(aSrc + (size_t)64 * KDIM + (kt)*32), \
      (LAS void*)(lds + (b)*4096 + 2048 + tid8), 16, 0, 0); \
  __builtin_amdgcn_global_load_lds((GAS void*)(bSrc + (kt)*32), \
      (LAS void*)(lds + 8192 + (b)*8192 + tid8), 16, 0, 0); \
  __builtin_amdgcn_global_load_lds((GAS void*)(bSrc + (size_t)64 * KDIM + (kt)*32), \
      (LAS void*)(lds + 8192 + (b)*8192 + 2048 + tid8), 16, 0, 0); \
  __builtin_amdgcn_global_load_lds((GAS void*)(bSrc + (size_t)128 * KDIM + (kt)*32), \
      (LAS void*)(lds + 8192 + (b)*8192 + 4096 + tid8), 16, 0, 0); \
  __builtin_amdgcn_global_load_lds((GAS void*)(bSrc + (size_t)192 * KDIM + (kt)*32), \
      (LAS void*)(lds + 8192 + (b)*8192 + 6144 + tid8), 16, 0, 0); } while (0)

  // ---- fragment reads: row&3 == l16&3 for every frag (16 | frag offsets) ----
  int colbase = ((lk ^ (l16 & 3)) << 3);
  int aRd = l16 * 32 + colbase;                 // + mi*512 + c*4096
  int bRd = wn * 2048 + l16 * 32 + colbase;     // + nj*512 + 8192 + c*8192

#define RD_A(c, mi) (*(const bf16x8*)(lds + (c)*4096 + aRd + (mi)*512))
#define RD_B(c, nj) (*(const bf16x8*)(lds + 8192 + (c)*8192 + bRd + (nj)*512))

  bf16x8 av[8];
  bf16x8 bv[4];
  f32x4 acc[8][4] = {};

#define READS(c) do { \
  bv[0] = RD_B(c,0); bv[1] = RD_B(c,1); bv[2] = RD_B(c,2); bv[3] = RD_B(c,3); \
  av[0] = RD_A(c,0); av[1] = RD_A(c,1); av[2] = RD_A(c,2); av[3] = RD_A(c,3); \
  av[4] = RD_A(c,4); av[5] = RD_A(c,5); av[6] = RD_A(c,6); av[7] = RD_A(c,7); } while (0)

#define MF(mi, nj) acc[mi][nj] = __builtin_amdgcn_mfma_f32_16x16x32_bf16( \
    av[mi], bv[nj], acc[mi][nj], 0, 0, 0)
#define MROW(mi) do { MF(mi,0); MF(mi,1); MF(mi,2); MF(mi,3); } while (0)
#define MFMAS() do { MROW(0); MROW(1); MROW(2); MROW(3); \
                     MROW(4); MROW(5); MROW(6); MROW(7); } while (0)

  // ---- prologue: kt0 -> buf0, kt1 -> buf1 ----
  STAGE(0, 0); STAGE(1, 1);
  VMC0();
  BAR();

  // ---- main loop: 63 iters x 2 K-tiles (kt 0..125), stages kt 2..127 ----
  for (int it = 0; it < 63; ++it) {
    int kA = 2 * it + 2, kB = 2 * it + 3;
    // kt = 2it, buf0
    READS(0); LGKM0(); BAR();
    STAGE(0, kA); SB0();
    PRIO(1); MFMAS(); PRIO(0);
    VMC6(); BAR();
    // kt = 2it+1, buf1
    READS(1); LGKM0(); BAR();
    STAGE(1, kB); SB0();
    PRIO(1); MFMAS(); PRIO(0);
    VMC6(); BAR();
  }
  // kt = 126, buf0 (no stage; full drain so kt127 visible to all)
  READS(0); LGKM0(); BAR();
  PRIO(1); MFMAS(); PRIO(0);
  VMC0(); BAR();
  // kt = 127, buf1
  READS(1); LGKM0();
  PRIO(1); MFMAS(); PRIO(0);

  // ---- C write: col = l16 + 16*nj + wn*64 (+n0), row = lk*4 + rr + 16*mi (+m0) ----
  int matc = n0 >> 12;
  int ncol = (n0 & 4095) + wn * 64;
  unsigned short* O = out + (size_t)matc * M_TOK * HIDDEN;
  float bb[4];
#pragma unroll
  for (int nj = 0; nj < 4; ++nj) bb[nj] = bias[n0 + wn * 64 + nj * 16 + l16];
#pragma unroll
  for (int mi = 0; mi < 8; ++mi) {
#pragma unroll
    for (int rr = 0; rr < 4; ++rr) {
      int row = m0 + mi * 16 + lk * 4 + rr;
      size_t rb = (size_t)row * HIDDEN + ncol + l16;
#pragma unroll
      for (int nj = 0; nj < 4; ++nj)
        O[rb + nj * 16] = f2bf(acc[mi][nj][rr] + bb[nj]);
    }
  }
}

// ---------- per-token 32x32 head attention ----------
__global__ __launch_bounds__(256) void attn_kernel(const unsigned short* __restrict__ qkv,
                                                   float* __restrict__ out) {
  __shared__ float sQ[32 * 132];
  __shared__ float sK[32 * 132];
  __shared__ float sV[32 * 132];
  __shared__ float sP[32 * 33];

  int m = blockIdx.x;
  int tid = threadIdx.x;
  const unsigned short* gq = qkv + (size_t)m * HIDDEN;
  const unsigned short* gk = gq + (size_t)M_TOK * HIDDEN;
  const unsigned short* gv = gk + (size_t)M_TOK * HIDDEN;

  int row = tid >> 3;
  int cb = (tid & 7) << 4;
  int go = row * 128 + cb;
  int lo = row * 132 + cb;
  {
    u16x8 x0 = *(const u16x8*)(gq + go);
    u16x8 x1 = *(const u16x8*)(gq + go + 8);
#pragma unroll
    for (int j = 0; j < 8; ++j) { sQ[lo + j] = bf2f(x0[j]); sQ[lo + 8 + j] = bf2f(x1[j]); }
    x0 = *(const u16x8*)(gk + go);
    x1 = *(const u16x8*)(gk + go + 8);
#pragma unroll
    for (int j = 0; j < 8; ++j) { sK[lo + j] = bf2f(x0[j]); sK[lo + 8 + j] = bf2f(x1[j]); }
    x0 = *(const u16x8*)(gv + go);
    x1 = *(const u16x8*)(gv + go + 8);
#pragma unroll
    for (int j = 0; j < 8; ++j) { sV[lo + j] = bf2f(x0[j]); sV[lo + 8 + j] = bf2f(x1[j]); }
  }
  __syncthreads();

  int h = tid >> 3;
  int t4 = (tid & 7) << 2;
  const f32x4* qr = (const f32x4*)(sQ + h * 132);
  const f32x4* k0 = (const f32x4*)(sK + (t4 + 0) * 132);
  const f32x4* k1 = (const f32x4*)(sK + (t4 + 1) * 132);
  const f32x4* k2 = (const f32x4*)(sK + (t4 + 2) * 132);
  const f32x4* k3 = (const f32x4*)(sK + (t4 + 3) * 132);
  float s0 = 0.f, s1 = 0.f, s2 = 0.f, s3 = 0.f;
#pragma unroll
  for (int d = 0; d < 32; ++d) {
    f32x4 q = qr[d];
    f32x4 a = k0[d]; s0 += q.x * a.x + q.y * a.y + q.z * a.z + q.w * a.w;
    f32x4 b = k1[d]; s1 += q.x * b.x + q.y * b.y + q.z * b.z + q.w * b.w;
    f32x4 c = k2[d]; s2 += q.x * c.x + q.y * c.y + q.z * c.z + q.w * c.w;
    f32x4 e = k3[d]; s3 += q.x * e.x + q.y * e.y + q.z * e.z + q.w * e.w;
  }
  const float scale = 0.08838834764831845f;  // 1/sqrt(128)
  s0 *= scale; s1 *= scale; s2 *= scale; s3 *= scale;
  float mx = fmaxf(fmaxf(s0, s1), fmaxf(s2, s3));
  mx = fmaxf(mx, __shfl_xor(mx, 1));
  mx = fmaxf(mx, __shfl_xor(mx, 2));
  mx = fmaxf(mx, __shfl_xor(mx, 4));
  float e0 = __expf(s0 - mx), e1 = __expf(s1 - mx), e2 = __expf(s2 - mx), e3 = __expf(s3 - mx);
  float sum = e0 + e1 + e2 + e3;
  sum += __shfl_xor(sum, 1);
  sum += __shfl_xor(sum, 2);
  sum += __shfl_xor(sum, 4);
  float inv = 1.0f / sum;
  sP[h * 33 + t4 + 0] = e0 * inv;
  sP[h * 33 + t4 + 1] = e1 * inv;
  sP[h * 33 + t4 + 2] = e2 * inv;
  sP[h * 33 + t4 + 3] = e3 * inv;
  __syncthreads();

  int d0 = (tid & 7) << 4;
  f32x4 o0 = {0.f, 0.f, 0.f, 0.f}, o1 = o0, o2 = o0, o3 = o0;
  const float* pr = sP + h * 33;
#pragma unroll
  for (int t = 0; t < 32; ++t) {
    float p = pr[t];
    const f32x4* vr = (const f32x4*)(sV + t * 132 + d0);
    o0 += p * vr[0];
    o1 += p * vr[1];
    o2 += p * vr[2];
    o3 += p * vr[3];
  }
  f32x4* op = (f32x4*)(out + (size_t)m * HIDDEN + h * 128 + d0);
  op[0] = o0; op[1] = o1; op[2] = o2; op[3] = o3;
}

extern "C" void kernel_launch(void* const* d_in, const int* in_sizes, int n_in,
                              void* d_out, int out_size, void* d_ws, size_t ws_size,
                              hipStream_t stream) {
  const float* hs = (const float*)d_in[0];
  const float* wq = (const float*)d_in[1];
  const float* bq = (const float*)d_in[2];
  const float* wk = (const float*)d_in[3];
  const float* bk = (const float*)d_in[4];
  const float* wv = (const float*)d_in[5];
  const float* bv = (const float*)d_in[6];
  // wl/bl latent projection: unused by output — skipped.

  char* ws = (char*)d_ws;
  const size_t HS_OFF = 0;                    // 64 MiB
  const size_t W_OFF = 67108864;              // 96 MiB
  const size_t QKV_OFF = 167772160;           // 192 MiB
  const size_t BIAS_OFF = 369098752;          // 48 KiB
  const size_t NEED = 369147904;
  if (ws_size < NEED) return;

  unsigned short* hsb = (unsigned short*)(ws + HS_OFF);
  unsigned short* wb = (unsigned short*)(ws + W_OFF);
  unsigned short* qkv = (unsigned short*)(ws + QKV_OFF);
  float* bias = (float*)(ws + BIAS_OFF);

  cvt_fused<<<41008, 256, 0, stream>>>(hs, wq, wk, wv, bq, bk, bv, hsb, wb, bias);
  gemm_qkv<<<3072, 256, 0, stream>>>(hsb, wb, bias, qkv);   // 8 XCD x 8 tm x 48 tn
  attn_kernel<<<8192, 256, 0, stream>>>(qkv, (float*)d_out);
}

// Round 10
// 1063.854 us; speedup vs baseline: 1.0319x; 1.0319x over previous
//
#include <hip/hip_runtime.h>
#include <stdint.h>

#define HIDDEN 4096
#define M_TOK 8192   // B*S
#define KDIM 4096

typedef __attribute__((ext_vector_type(8))) __bf16 bf16x8;
typedef __attribute__((ext_vector_type(4))) float f32x4;
typedef __attribute__((ext_vector_type(8))) unsigned short u16x8;

#define GAS __attribute__((address_space(1)))
#define LAS __attribute__((address_space(3)))

__device__ __forceinline__ unsigned short f2bf(float f) {
  unsigned int u = __float_as_uint(f);
  u += 0x7FFFu + ((u >> 16) & 1u);
  return (unsigned short)(u >> 16);
}
__device__ __forceinline__ float bf2f(unsigned short b) {
  return __uint_as_float(((unsigned int)b) << 16);
}

// ---------- fused fp32->bf16 conversions + bias pack, one launch ----------
__device__ __forceinline__ void cvt8(const float* __restrict__ in,
                                     unsigned short* __restrict__ out, int i) {
  const f32x4* p = (const f32x4*)in + (size_t)2 * i;
  f32x4 a = p[0], b = p[1];
  u16x8 o;
  o[0] = f2bf(a.x); o[1] = f2bf(a.y); o[2] = f2bf(a.z); o[3] = f2bf(a.w);
  o[4] = f2bf(b.x); o[5] = f2bf(b.y); o[6] = f2bf(b.z); o[7] = f2bf(b.w);
  ((u16x8*)out)[i] = o;
}

__global__ __launch_bounds__(256) void cvt_fused(
    const float* __restrict__ hs, const float* __restrict__ wq,
    const float* __restrict__ wk, const float* __restrict__ wv,
    const float* __restrict__ bq, const float* __restrict__ bk,
    const float* __restrict__ bv,
    unsigned short* __restrict__ hsb, unsigned short* __restrict__ wb,
    float* __restrict__ bias) {
  int b = blockIdx.x;
  int tid = threadIdx.x;
  if (b < 16384) {                      // hs
    cvt8(hs, hsb, b * 256 + tid);
  } else if (b < 24576) {               // wq
    cvt8(wq, wb, (b - 16384) * 256 + tid);
  } else if (b < 32768) {               // wk
    cvt8(wk, wb + 16777216, (b - 24576) * 256 + tid);
  } else if (b < 40960) {               // wv
    cvt8(wv, wb + 33554432, (b - 32768) * 256 + tid);
  } else {                              // bias pack
    int i = (b - 40960) * 256 + tid;
    float v = (i < 4096) ? bq[i] : (i < 8192) ? bk[i - 4096] : bv[i - 8192];
    bias[i] = v;
  }
}

// ============================================================================
// 128x192 QKV GEMM, BK=64, 256 thr = 4 waves (2M x 2N), 2 blocks/CU.
// R9 post-mortem: (a) ONLY 128-B LDS rows + chunk^=(row&7) measure 0 bank
// conflicts (64-B-row variants all measure +4 cyc/read) -> BK=64 mandatory.
// (b) acc[8][4]=128 AGPR made 232 unified regs -> never got extra blocks.
// This config: acc[4][6]=96 AGPR (~210 regs, 2 waves/SIMD), LDS =
// A[2][128][64] + B[2][192][64] = 81920 B -> 2 blocks/CU (exactly 160 KiB).
// Per K-tile per block: LDS 960 cyc vs MFMA 933 (ratio 1.03, best tried);
// cross-block overlap (m114) fills the read/barrier phases.
// Schedule: R6's proven 2-barrier K-tile, vmcnt(10) (10 gloads/K-tile,
// 2-deep prefetch). BN=192 crosses q/k/v boundaries -> per-nj matrix index
// in epilogue (16-aligned col groups never straddle a 4096 boundary).
// ============================================================================
#define BAR() __builtin_amdgcn_s_barrier()
#define PRIO(p) __builtin_amdgcn_s_setprio(p)
#define VMC10() asm volatile("s_waitcnt vmcnt(10)" ::: "memory")
#define VMC0() asm volatile("s_waitcnt vmcnt(0)" ::: "memory")
#define LGKM0() do { asm volatile("s_waitcnt lgkmcnt(0)" ::: "memory"); \
  __builtin_amdgcn_sched_barrier(0); } while (0)
#define SB0() __builtin_amdgcn_sched_barrier(0)

__global__ __launch_bounds__(256, 2) void gemm_qkv(
    const unsigned short* __restrict__ A,   // [8192][4096] bf16
    const unsigned short* __restrict__ W,   // [12288][4096] bf16 (wq;wk;wv)
    const float* __restrict__ bias,         // [12288]
    unsigned short* __restrict__ out) {     // [3][8192][4096] bf16
  // A: 2 bufs x 128 rows x 64 shorts = 16384 shorts; B: 2 x 192 x 64 = 24576.
  __shared__ __attribute__((aligned(16))) unsigned short lds[40960];  // 80 KiB

  int tid = threadIdx.x;       // 0..255
  int lane = tid & 63;
  int w = tid >> 6;
  int wm = w >> 1;             // 0..1 -> rows wm*64
  int wn = w & 1;              // 0..1 -> cols wn*96
  int l16 = lane & 15;
  int lk = lane >> 4;

  // ---- 2D XCD slab map (grid = 4096 = 8 XCD * 8 tm * 64 tn) ----
  int bid = blockIdx.x;
  int xcd = bid & 7;
  int local = bid >> 3;        // 0..511
  int r = local >> 6;          // 0..7 tn-round
  int i = local & 63;          // 0..63 co-resident (2/CU * 32 CU)
  int tm = (xcd << 3) + (i >> 3);   // 0..63
  int tn = (r << 3) + (i & 7);      // 0..63
  int m0 = tm << 7;            // *128
  int n0 = tn * 192;

  // ---- staging source: pre-swizzled global col (3-bit XOR by row&7) ----
  int rsub = tid >> 3;                                   // 0..31
  int ce = ((tid & 7) << 3) ^ ((rsub & 7) << 3);         // col elems, swizzled
  const unsigned short* aSrc = A + (size_t)(m0 + rsub) * KDIM + ce;
  const unsigned short* bSrc = W + (size_t)(n0 + rsub) * KDIM + ce;
  int tid8 = tid * 8;          // 16 B/thread; 256 thr = 32 rows of 128 B

#define GL(src, dst) __builtin_amdgcn_global_load_lds((GAS void*)(src), (LAS void*)(dst), 16, 0, 0)
#define STAGE(b, kt) do { \
  GL(aSrc + (kt)*64,                     lds + (b)*8192 + tid8); \
  GL(aSrc + (size_t)32*KDIM + (kt)*64,   lds + (b)*8192 + 2048 + tid8); \
  GL(aSrc + (size_t)64*KDIM + (kt)*64,   lds + (b)*8192 + 4096 + tid8); \
  GL(aSrc + (size_t)96*KDIM + (kt)*64,   lds + (b)*8192 + 6144 + tid8); \
  GL(bSrc + (kt)*64,                     lds + 16384 + (b)*12288 + tid8); \
  GL(bSrc + (size_t)32*KDIM + (kt)*64,   lds + 16384 + (b)*12288 + 2048 + tid8); \
  GL(bSrc + (size_t)64*KDIM + (kt)*64,   lds + 16384 + (b)*12288 + 4096 + tid8); \
  GL(bSrc + (size_t)96*KDIM + (kt)*64,   lds + 16384 + (b)*12288 + 6144 + tid8); \
  GL(bSrc + (size_t)128*KDIM + (kt)*64,  lds + 16384 + (b)*12288 + 8192 + tid8); \
  GL(bSrc + (size_t)160*KDIM + (kt)*64,  lds + 16384 + (b)*12288 + 10240 + tid8); } while (0)

  // ---- fragment reads: EXACT R3 pattern (128-B rows, 3-bit XOR, 0 conflicts) ----
  int colbase = (lk << 3) ^ ((l16 & 7) << 3);
  int aRd = wm * 4096 + l16 * 64 + colbase;      // + mi*1024 (16 rows), ^ks*32
  int bRd = wn * 6144 + l16 * 64 + colbase;      // + nj*1024, ^ks*32

#define RD_A(c, mi, ks) (*(const bf16x8*)(lds + (c)*8192 + (((aRd) + (mi)*1024) ^ ((ks)*32))))
#define RD_B(c, nj, ks) (*(const bf16x8*)(lds + 16384 + (c)*12288 + (((bRd) + (nj)*1024) ^ ((ks)*32))))

  bf16x8 av[4][2];
  bf16x8 bv[6][2];
  f32x4 acc[4][6] = {};

#define READS(c) do { \
  bv[0][0]=RD_B(c,0,0); bv[0][1]=RD_B(c,0,1); bv[1][0]=RD_B(c,1,0); bv[1][1]=RD_B(c,1,1); \
  bv[2][0]=RD_B(c,2,0); bv[2][1]=RD_B(c,2,1); bv[3][0]=RD_B(c,3,0); bv[3][1]=RD_B(c,3,1); \
  bv[4][0]=RD_B(c,4,0); bv[4][1]=RD_B(c,4,1); bv[5][0]=RD_B(c,5,0); bv[5][1]=RD_B(c,5,1); \
  av[0][0]=RD_A(c,0,0); av[0][1]=RD_A(c,0,1); av[1][0]=RD_A(c,1,0); av[1][1]=RD_A(c,1,1); \
  av[2][0]=RD_A(c,2,0); av[2][1]=RD_A(c,2,1); av[3][0]=RD_A(c,3,0); av[3][1]=RD_A(c,3,1); } while (0)

#define MF(mi, nj, ks) acc[mi][nj] = __builtin_amdgcn_mfma_f32_16x16x32_bf16( \
    av[mi][ks], bv[nj][ks], acc[mi][nj], 0, 0, 0)
#define MHALF(ks) do { \
  MF(0,0,ks); MF(0,1,ks); MF(0,2,ks); MF(0,3,ks); MF(0,4,ks); MF(0,5,ks); \
  MF(1,0,ks); MF(1,1,ks); MF(1,2,ks); MF(1,3,ks); MF(1,4,ks); MF(1,5,ks); \
  MF(2,0,ks); MF(2,1,ks); MF(2,2,ks); MF(2,3,ks); MF(2,4,ks); MF(2,5,ks); \
  MF(3,0,ks); MF(3,1,ks); MF(3,2,ks); MF(3,3,ks); MF(3,4,ks); MF(3,5,ks); } while (0)
#define MFMAS() do { MHALF(0); MHALF(1); } while (0)

  // ---- prologue: kt0 -> buf0, kt1 -> buf1; retire kt0 ----
  STAGE(0, 0); STAGE(1, 1);
  VMC10();
  BAR();

  // ---- main loop: 31 iters x 2 K-tiles (kt 0..61), stages kt 2..63 ----
  for (int it = 0; it < 31; ++it) {
    int kA = 2 * it + 2, kB = 2 * it + 3;
    // kt = 2it, buf0
    READS(0); LGKM0(); BAR();
    STAGE(0, kA); SB0();
    PRIO(1); MFMAS(); PRIO(0);
    VMC10(); BAR();
    // kt = 2it+1, buf1
    READS(1); LGKM0(); BAR();
    STAGE(1, kB); SB0();
    PRIO(1); MFMAS(); PRIO(0);
    VMC10(); BAR();
  }
  // kt = 62, buf0 (no stage; full drain so kt63 is visible to all waves)
  READS(0); LGKM0(); BAR();
  PRIO(1); MFMAS(); PRIO(0);
  VMC0(); BAR();
  // kt = 63, buf1
  READS(1); LGKM0();
  PRIO(1); MFMAS(); PRIO(0);

  // ---- C write: col = n0 + wn*96 + nj*16 + l16 (may cross q/k/v boundary;
  //      16-aligned group never straddles 4096), row = m0 + wm*64 + mi*16 + lk*4 + rr
  int colb = n0 + wn * 96;
  unsigned short* Onj[6];
  float bb[6];
#pragma unroll
  for (int nj = 0; nj < 6; ++nj) {
    int cg = colb + nj * 16 + l16;
    int mat = cg >> 12;
    Onj[nj] = out + (size_t)mat * M_TOK * HIDDEN + (cg & 4095);
    bb[nj] = bias[cg];
  }
#pragma unroll
  for (int mi = 0; mi < 4; ++mi) {
#pragma unroll
    for (int rr = 0; rr < 4; ++rr) {
      size_t rowoff = (size_t)(m0 + wm * 64 + mi * 16 + lk * 4 + rr) * HIDDEN;
#pragma unroll
      for (int nj = 0; nj < 6; ++nj)
        Onj[nj][rowoff] = f2bf(acc[mi][nj][rr] + bb[nj]);
    }
  }
}

// ---------- per-token 32x32 head attention ----------
__global__ __launch_bounds__(256) void attn_kernel(const unsigned short* __restrict__ qkv,
                                                   float* __restrict__ out) {
  __shared__ float sQ[32 * 132];
  __shared__ float sK[32 * 132];
  __shared__ float sV[32 * 132];
  __shared__ float sP[32 * 33];

  int m = blockIdx.x;
  int tid = threadIdx.x;
  const unsigned short* gq = qkv + (size_t)m * HIDDEN;
  const unsigned short* gk = gq + (size_t)M_TOK * HIDDEN;
  const unsigned short* gv = gk + (size_t)M_TOK * HIDDEN;

  int row = tid >> 3;
  int cb = (tid & 7) << 4;
  int go = row * 128 + cb;
  int lo = row * 132 + cb;
  {
    u16x8 x0 = *(const u16x8*)(gq + go);
    u16x8 x1 = *(const u16x8*)(gq + go + 8);
#pragma unroll
    for (int j = 0; j < 8; ++j) { sQ[lo + j] = bf2f(x0[j]); sQ[lo + 8 + j] = bf2f(x1[j]); }
    x0 = *(const u16x8*)(gk + go);
    x1 = *(const u16x8*)(gk + go + 8);
#pragma unroll
    for (int j = 0; j < 8; ++j) { sK[lo + j] = bf2f(x0[j]); sK[lo + 8 + j] = bf2f(x1[j]); }
    x0 = *(const u16x8*)(gv + go);
    x1 = *(const u16x8*)(gv + go + 8);
#pragma unroll
    for (int j = 0; j < 8; ++j) { sV[lo + j] = bf2f(x0[j]); sV[lo + 8 + j] = bf2f(x1[j]); }
  }
  __syncthreads();

  int h = tid >> 3;
  int t4 = (tid & 7) << 2;
  const f32x4* qr = (const f32x4*)(sQ + h * 132);
  const f32x4* k0 = (const f32x4*)(sK + (t4 + 0) * 132);
  const f32x4* k1 = (const f32x4*)(sK + (t4 + 1) * 132);
  const f32x4* k2 = (const f32x4*)(sK + (t4 + 2) * 132);
  const f32x4* k3 = (const f32x4*)(sK + (t4 + 3) * 132);
  float s0 = 0.f, s1 = 0.f, s2 = 0.f, s3 = 0.f;
#pragma unroll
  for (int d = 0; d < 32; ++d) {
    f32x4 q = qr[d];
    f32x4 a = k0[d]; s0 += q.x * a.x + q.y * a.y + q.z * a.z + q.w * a.w;
    f32x4 b = k1[d]; s1 += q.x * b.x + q.y * b.y + q.z * b.z + q.w * b.w;
    f32x4 c = k2[d]; s2 += q.x * c.x + q.y * c.y + q.z * c.z + q.w * c.w;
    f32x4 e = k3[d]; s3 += q.x * e.x + q.y * e.y + q.z * e.z + q.w * e.w;
  }
  const float scale = 0.08838834764831845f;  // 1/sqrt(128)
  s0 *= scale; s1 *= scale; s2 *= scale; s3 *= scale;
  float mx = fmaxf(fmaxf(s0, s1), fmaxf(s2, s3));
  mx = fmaxf(mx, __shfl_xor(mx, 1));
  mx = fmaxf(mx, __shfl_xor(mx, 2));
  mx = fmaxf(mx, __shfl_xor(mx, 4));
  float e0 = __expf(s0 - mx), e1 = __expf(s1 - mx), e2 = __expf(s2 - mx), e3 = __expf(s3 - mx);
  float sum = e0 + e1 + e2 + e3;
  sum += __shfl_xor(sum, 1);
  sum += __shfl_xor(sum, 2);
  sum += __shfl_xor(sum, 4);
  float inv = 1.0f / sum;
  sP[h * 33 + t4 + 0] = e0 * inv;
  sP[h * 33 + t4 + 1] = e1 * inv;
  sP[h * 33 + t4 + 2] = e2 * inv;
  sP[h * 33 + t4 + 3] = e3 * inv;
  __syncthreads();

  int d0 = (tid & 7) << 4;
  f32x4 o0 = {0.f, 0.f, 0.f, 0.f}, o1 = o0, o2 = o0, o3 = o0;
  const float* pr = sP + h * 33;
#pragma unroll
  for (int t = 0; t < 32; ++t) {
    float p = pr[t];
    const f32x4* vr = (const f32x4*)(sV + t * 132 + d0);
    o0 += p * vr[0];
    o1 += p * vr[1];
    o2 += p * vr[2];
    o3 += p * vr[3];
  }
  f32x4* op = (f32x4*)(out + (size_t)m * HIDDEN + h * 128 + d0);
  op[0] = o0; op[1] = o1; op[2] = o2; op[3] = o3;
}

extern "C" void kernel_launch(void* const* d_in, const int* in_sizes, int n_in,
                              void* d_out, int out_size, void* d_ws, size_t ws_size,
                              hipStream_t stream) {
  const float* hs = (const float*)d_in[0];
  const float* wq = (const float*)d_in[1];
  const float* bq = (const float*)d_in[2];
  const float* wk = (const float*)d_in[3];
  const float* bk = (const float*)d_in[4];
  const float* wv = (const float*)d_in[5];
  const float* bv = (const float*)d_in[6];
  // wl/bl latent projection: unused by output — skipped.

  char* ws = (char*)d_ws;
  const size_t HS_OFF = 0;                    // 64 MiB
  const size_t W_OFF = 67108864;              // 96 MiB
  const size_t QKV_OFF = 167772160;           // 192 MiB
  const size_t BIAS_OFF = 369098752;          // 48 KiB
  const size_t NEED = 369147904;
  if (ws_size < NEED) return;

  unsigned short* hsb = (unsigned short*)(ws + HS_OFF);
  unsigned short* wb = (unsigned short*)(ws + W_OFF);
  unsigned short* qkv = (unsigned short*)(ws + QKV_OFF);
  float* bias = (float*)(ws + BIAS_OFF);

  cvt_fused<<<41008, 256, 0, stream>>>(hs, wq, wk, wv, bq, bk, bv, hsb, wb, bias);
  gemm_qkv<<<4096, 256, 0, stream>>>(hsb, wb, bias, qkv);   // 8 XCD x 8 tm x 64 tn
  attn_kernel<<<8192, 256, 0, stream>>>(qkv, (float*)d_out);
}

// Round 11
// 743.993 us; speedup vs baseline: 1.4756x; 1.4299x over previous
//
#include <hip/hip_runtime.h>
#include <stdint.h>

#define HIDDEN 4096
#define M_TOK 8192   // B*S
#define KDIM 4096

typedef __attribute__((ext_vector_type(8))) __bf16 bf16x8;
typedef __attribute__((ext_vector_type(4))) float f32x4;
typedef __attribute__((ext_vector_type(16))) float f32x16;
typedef __attribute__((ext_vector_type(8))) unsigned short u16x8;
typedef __attribute__((ext_vector_type(4))) unsigned int u32x4;

#define GAS __attribute__((address_space(1)))
#define LAS __attribute__((address_space(3)))

__device__ __forceinline__ unsigned short f2bf(float f) {
  unsigned int u = __float_as_uint(f);
  u += 0x7FFFu + ((u >> 16) & 1u);
  return (unsigned short)(u >> 16);
}
__device__ __forceinline__ float bf2f(unsigned short b) {
  return __uint_as_float(((unsigned int)b) << 16);
}

// ---------- fused fp32->bf16 conversions + bias pack, one launch ----------
__device__ __forceinline__ void cvt8(const float* __restrict__ in,
                                     unsigned short* __restrict__ out, int i) {
  const f32x4* p = (const f32x4*)in + (size_t)2 * i;
  f32x4 a = p[0], b = p[1];
  u16x8 o;
  o[0] = f2bf(a.x); o[1] = f2bf(a.y); o[2] = f2bf(a.z); o[3] = f2bf(a.w);
  o[4] = f2bf(b.x); o[5] = f2bf(b.y); o[6] = f2bf(b.z); o[7] = f2bf(b.w);
  ((u16x8*)out)[i] = o;
}

__global__ __launch_bounds__(256) void cvt_fused(
    const float* __restrict__ hs, const float* __restrict__ wq,
    const float* __restrict__ wk, const float* __restrict__ wv,
    const float* __restrict__ bq, const float* __restrict__ bk,
    const float* __restrict__ bv,
    unsigned short* __restrict__ hsb, unsigned short* __restrict__ wb,
    float* __restrict__ bias) {
  int b = blockIdx.x;
  int tid = threadIdx.x;
  if (b < 16384) {                      // hs
    cvt8(hs, hsb, b * 256 + tid);
  } else if (b < 24576) {               // wq
    cvt8(wq, wb, (b - 16384) * 256 + tid);
  } else if (b < 32768) {               // wk
    cvt8(wk, wb + 16777216, (b - 24576) * 256 + tid);
  } else if (b < 40960) {               // wv
    cvt8(wv, wb + 33554432, (b - 32768) * 256 + tid);
  } else {                              // bias pack
    int i = (b - 40960) * 256 + tid;
    float v = (i < 4096) ? bq[i] : (i < 8192) ? bk[i - 4096] : bv[i - 8192];
    bias[i] = v;
  }
}

// ============================================================================
// 256x256 QKV GEMM — R8 config, reverted verbatim (session best: 660us,
// MfmaUtil 60%, conflicts 0, FETCH 0.59e6). R10 lesson: all occupancy-driven
// tile shrinks (R4/R6/R9/R10) lose to this config on FETCH blowup and/or the
// bank-conflict law (only 128B rows + chunk^=(row&7) measure 0).
// ============================================================================
#define BAR() __builtin_amdgcn_s_barrier()
#define PRIO(p) __builtin_amdgcn_s_setprio(p)
#define VMC6() asm volatile("s_waitcnt vmcnt(6)" ::: "memory")
#define VMC0() asm volatile("s_waitcnt vmcnt(0)" ::: "memory")
#define LGKM0() do { asm volatile("s_waitcnt lgkmcnt(0)" ::: "memory"); \
  __builtin_amdgcn_sched_barrier(0); } while (0)
#define SB0() __builtin_amdgcn_sched_barrier(0)

__global__ __launch_bounds__(512, 2) void gemm_qkv(
    const unsigned short* __restrict__ A,   // [8192][4096] bf16
    const unsigned short* __restrict__ W,   // [12288][4096] bf16 (wq;wk;wv)
    const float* __restrict__ bias,         // [12288]
    unsigned short* __restrict__ out) {     // [3][8192][4096] bf16
  __shared__ __attribute__((aligned(16))) unsigned short lds[65536];  // 128 KiB

  int tid = threadIdx.x;
  int lane = tid & 63;
  int w = tid >> 6;
  int wm = w >> 2;        // 0..1 -> rows wm*128
  int wn = w & 3;         // 0..3 -> cols wn*64
  int l16 = lane & 15;
  int lk = lane >> 4;

  // ---- 2D XCD slab mapping (bijective; grid = 1536 = 8 XCD * 4 tm * 48 tn) ----
  int bid = blockIdx.x;
  int xcd = bid & 7;
  int local = bid >> 3;       // 0..191
  int r = local >> 5;         // 0..5 tn-round
  int i = local & 31;         // 0..31 co-resident slot
  int tm = (xcd << 2) + (i >> 3);
  int tn = (r << 3) + (i & 7);
  int m0 = tm << 8, n0 = tn << 8;

  // ---- staging source: pre-swizzled global col (3-bit XOR by row&7) ----
  int rp = tid >> 3;
  int ce = ((tid & 7) << 3) ^ ((rp & 7) << 3);
  const unsigned short* aSrc = A + (size_t)(m0 + rp) * KDIM + ce;
  const unsigned short* bSrc = W + (size_t)(n0 + rp) * KDIM + ce;
  int tid8 = tid * 8;

#define STA(b, h, kt) do { \
  __builtin_amdgcn_global_load_lds((GAS void*)(aSrc + (size_t)((h)*128) * KDIM + (kt)*64), \
      (LAS void*)(lds + (b)*16384 + (h)*8192 + tid8), 16, 0, 0); \
  __builtin_amdgcn_global_load_lds((GAS void*)(aSrc + (size_t)((h)*128 + 64) * KDIM + (kt)*64), \
      (LAS void*)(lds + (b)*16384 + (h)*8192 + 4096 + tid8), 16, 0, 0); } while (0)
#define STB(b, h, kt) do { \
  __builtin_amdgcn_global_load_lds((GAS void*)(bSrc + (size_t)((h)*128) * KDIM + (kt)*64), \
      (LAS void*)(lds + 32768 + (b)*16384 + (h)*8192 + tid8), 16, 0, 0); \
  __builtin_amdgcn_global_load_lds((GAS void*)(bSrc + (size_t)((h)*128 + 64) * KDIM + (kt)*64), \
      (LAS void*)(lds + 32768 + (b)*16384 + (h)*8192 + 4096 + tid8), 16, 0, 0); } while (0)

  // ---- fragment read addressing: R3 pattern (0 conflicts measured) ----
  int colbase = (lk << 3) ^ ((l16 & 7) << 3);
  int aRd = wm * 8192 + l16 * 64 + colbase;
  int bRd = (wn >> 1) * 8192 + (wn & 1) * 4096 + l16 * 64 + colbase;

#define RD_A(c, mi, ks) (*(const bf16x8*)(lds + (c)*16384 + (((aRd) + (mi)*1024) ^ ((ks)*32))))
#define RD_B(c, nj, ks) (*(const bf16x8*)(lds + 32768 + (c)*16384 + (((bRd) + (nj)*1024) ^ ((ks)*32))))

  bf16x8 av[8][2];
  bf16x8 bv[4][2];
  f32x4 acc[8][4] = {};

#define RP1(c) do { \
  bv[0][0]=RD_B(c,0,0); bv[0][1]=RD_B(c,0,1); bv[1][0]=RD_B(c,1,0); bv[1][1]=RD_B(c,1,1); \
  bv[2][0]=RD_B(c,2,0); bv[2][1]=RD_B(c,2,1); bv[3][0]=RD_B(c,3,0); bv[3][1]=RD_B(c,3,1); \
  av[0][0]=RD_A(c,0,0); av[0][1]=RD_A(c,0,1); av[1][0]=RD_A(c,1,0); av[1][1]=RD_A(c,1,1); } while (0)
#define RP2(c) do { \
  av[2][0]=RD_A(c,2,0); av[2][1]=RD_A(c,2,1); av[3][0]=RD_A(c,3,0); av[3][1]=RD_A(c,3,1); \
  av[4][0]=RD_A(c,4,0); av[4][1]=RD_A(c,4,1); av[5][0]=RD_A(c,5,0); av[5][1]=RD_A(c,5,1); } while (0)
#define RP3(c) do { \
  av[6][0]=RD_A(c,6,0); av[6][1]=RD_A(c,6,1); av[7][0]=RD_A(c,7,0); av[7][1]=RD_A(c,7,1); } while (0)

#define MFMA2(mi, nj) do { \
  acc[mi][nj] = __builtin_amdgcn_mfma_f32_16x16x32_bf16(av[mi][0], bv[nj][0], acc[mi][nj], 0, 0, 0); \
  acc[mi][nj] = __builtin_amdgcn_mfma_f32_16x16x32_bf16(av[mi][1], bv[nj][1], acc[mi][nj], 0, 0, 0); } while (0)
#define MM(mi) do { MFMA2(mi,0); MFMA2(mi,1); MFMA2(mi,2); MFMA2(mi,3); } while (0)

#define KTILE(c, ka, kb) do { \
  STA(!(c), 1, ka); \
  BAR(); LGKM0(); PRIO(1); MM(0); MM(1); RP2(c); PRIO(0); SB0(); BAR(); \
  STB(c, 0, kb); \
  BAR(); LGKM0(); PRIO(1); MM(2); MM(3); RP3(c); PRIO(0); SB0(); BAR(); \
  STB(c, 1, kb); \
  BAR(); LGKM0(); PRIO(1); MM(4); MM(5); PRIO(0); SB0(); BAR(); \
  STA(c, 0, kb); VMC6(); \
  BAR(); SB0(); PRIO(1); MM(6); MM(7); RP1(!(c)); PRIO(0); SB0(); BAR(); } while (0)

  // ---- prologue ----
  STB(0, 0, 0); STB(0, 1, 0); STA(0, 0, 0); STA(0, 1, 0);
  STB(1, 0, 1); STB(1, 1, 1); STA(1, 0, 1);
  VMC0();
  BAR();
  RP1(0);

  for (int it = 0; it < 31; ++it) {
    int k1 = 2 * it + 1, k2 = 2 * it + 2, k3 = 2 * it + 3;
    KTILE(0, k1, k2);
    KTILE(1, k2, k3);
  }
  // ---- epilogue: kt62 (buf0; stage only A1 of kt63; full drain), kt63 ----
  STA(1, 1, 63);
  BAR(); LGKM0(); PRIO(1); MM(0); MM(1); RP2(0); PRIO(0); SB0(); BAR();
  BAR(); LGKM0(); PRIO(1); MM(2); MM(3); RP3(0); PRIO(0); SB0(); BAR();
  BAR(); LGKM0(); PRIO(1); MM(4); MM(5); PRIO(0); SB0(); BAR();
  VMC0();
  BAR(); SB0(); PRIO(1); MM(6); MM(7); RP1(1); PRIO(0); SB0(); BAR();
  BAR(); LGKM0(); PRIO(1); MM(0); MM(1); RP2(1); PRIO(0); SB0(); BAR();
  BAR(); LGKM0(); PRIO(1); MM(2); MM(3); RP3(1); PRIO(0); SB0(); BAR();
  BAR(); LGKM0(); PRIO(1); MM(4); MM(5); PRIO(0); SB0(); BAR();
  BAR(); LGKM0(); PRIO(1); MM(6); MM(7); PRIO(0);

  // ---- C write ----
  int matc = n0 >> 12;
  int ncol = (n0 & 4095) + wn * 64;
  unsigned short* O = out + (size_t)matc * M_TOK * HIDDEN;
  float bb[4];
#pragma unroll
  for (int nj = 0; nj < 4; ++nj) bb[nj] = bias[n0 + wn * 64 + nj * 16 + l16];
#pragma unroll
  for (int mi = 0; mi < 8; ++mi) {
#pragma unroll
    for (int rr = 0; rr < 4; ++rr) {
      int row = m0 + wm * 128 + mi * 16 + lk * 4 + rr;
      size_t rb = (size_t)row * HIDDEN + ncol + l16;
#pragma unroll
      for (int nj = 0; nj < 4; ++nj)
        O[rb + nj * 16] = f2bf(acc[mi][nj][rr] + bb[nj]);
    }
  }
}

// ============================================================================
// MFMA per-token attention: 1 wave = 1 token, 4 tokens/block, ZERO barriers.
// R10 post-mortem: old attn was VALU-bound (~1200 inst/thread ~ 6750 cyc/blk).
// QK^T and PV are MFMA-shaped (32x32, K=128/32) and q/k/v are already bf16.
// Fragment layouts hardware-verified by R4's passing run:
//   A/B elem j = M[l&31][ks*16 + (l>>5)*8 + j];  C: col=l&31,
//   row = (r&3) + 8*(r>>2) + 4*(l>>5).
// scores C[t][h] (A=k, B=q) -> softmax over t = 16-reg reduce + shfl_xor(32).
// P -> bf16 pack + partner swap + lg-select builds PV's A-frag in-register.
// V transposed to per-wave LDS tile Vt[d][t-chunk swizzled by d&3]:
//   write banks 2-way, read b128 banks 2-way, 16B-aligned. Wave-private.
// ============================================================================
__global__ __launch_bounds__(256) void attn_mfma(const unsigned short* __restrict__ qkv,
                                                 float* __restrict__ out) {
  __shared__ unsigned short vt[4 * 4096];   // 32 KiB: per-wave 128x32 (8 KiB)

  int tid = threadIdx.x;
  int w = tid >> 6;
  int lane = tid & 63;
  int l31 = lane & 31;
  int lg = lane >> 5;
  int m = blockIdx.x * 4 + w;

  const unsigned short* gq = qkv + (size_t)m * HIDDEN;
  const unsigned short* gk = gq + (size_t)M_TOK * HIDDEN;
  const unsigned short* gv = gk + (size_t)M_TOK * HIDDEN;
  unsigned short* vtw = vt + w * 4096;

  // ---- q/k fragments straight from global: frag kc elem j = x[l31][kc*16+lg*8+j]
  bf16x8 kf[8], qf[8];
#pragma unroll
  for (int kc = 0; kc < 8; ++kc) {
    kf[kc] = *(const bf16x8*)(gk + l31 * 128 + kc * 16 + lg * 8);
    qf[kc] = *(const bf16x8*)(gq + l31 * 128 + kc * 16 + lg * 8);
  }

  // ---- V -> LDS transposed: Vt[d][slot] where slot=(t>>3)^(d&3), elem t&7.
  // lane holds v[t=l31][c0..c0+7], c0 = lg*64 + i*8.
  {
    int t = l31;
#pragma unroll
    for (int i = 0; i < 8; ++i) {
      int c0 = lg * 64 + i * 8;
      u16x8 v8 = *(const u16x8*)(gv + t * 128 + c0);
#pragma unroll
      for (int j = 0; j < 8; ++j) {
        int d = c0 + j;
        vtw[d * 32 + (((t >> 3) ^ (d & 3)) << 3) + (t & 7)] = v8[j];
      }
    }
  }

  // ---- scores C[t][h] = sum_k k[t][.]*q[h][.]
  f32x16 C = {};
#pragma unroll
  for (int kc = 0; kc < 8; ++kc)
    C = __builtin_amdgcn_mfma_f32_32x32x16_bf16(kf[kc], qf[kc], C, 0, 0, 0);

  // ---- softmax over t (rows): 16 regs here + 16 in partner lane (lg^1)
  const float scale = 0.08838834764831845f;  // 1/sqrt(128)
  float p[16];
#pragma unroll
  for (int rr = 0; rr < 16; ++rr) p[rr] = C[rr] * scale;
  float mx = p[0];
#pragma unroll
  for (int rr = 1; rr < 16; ++rr) mx = fmaxf(mx, p[rr]);
  mx = fmaxf(mx, __shfl_xor(mx, 32));
  float s = 0.f;
#pragma unroll
  for (int rr = 0; rr < 16; ++rr) { p[rr] = __expf(p[rr] - mx); s += p[rr]; }
  s += __shfl_xor(s, 32);
  float inv = 1.0f / s;
#pragma unroll
  for (int rr = 0; rr < 16; ++rr) p[rr] *= inv;

  // ---- build PV A-frags: lane l31=h needs P[h][t'] for t' = kc*16+lg*8+j.
  // self (lg) holds t in {0-3,8-11,16-19,24-27}+4lg as reg pairs; partner has rest.
  unsigned int pk[8], op[8];
#pragma unroll
  for (int i = 0; i < 8; ++i) {
    pk[i] = (unsigned int)f2bf(p[2 * i]) | ((unsigned int)f2bf(p[2 * i + 1]) << 16);
    op[i] = (unsigned int)__shfl_xor((int)pk[i], 32);
  }
  union { u32x4 u; bf16x8 b; } A0, A1;
  A0.u = lg ? (u32x4){op[2], op[3], pk[2], pk[3]} : (u32x4){pk[0], pk[1], op[0], op[1]};
  A1.u = lg ? (u32x4){op[6], op[7], pk[6], pk[7]} : (u32x4){pk[4], pk[5], op[4], op[5]};

  // ---- PV: D[h][dc*32+l31] = sum_t P[h][t] V[t][d]; B from Vt rows (b128).
  asm volatile("s_waitcnt lgkmcnt(0)" ::: "memory");
  __builtin_amdgcn_sched_barrier(0);
  float* po = out + (size_t)m * HIDDEN;
#pragma unroll
  for (int dc = 0; dc < 4; ++dc) {
    int row = dc * 32 + l31;
    bf16x8 B0 = *(const bf16x8*)(vtw + row * 32 + (((0 << 1) + lg) ^ (l31 & 3)) * 8);
    bf16x8 B1 = *(const bf16x8*)(vtw + row * 32 + (((1 << 1) + lg) ^ (l31 & 3)) * 8);
    f32x16 D = {};
    D = __builtin_amdgcn_mfma_f32_32x32x16_bf16(A0.b, B0, D, 0, 0, 0);
    D = __builtin_amdgcn_mfma_f32_32x32x16_bf16(A1.b, B1, D, 0, 0, 0);
#pragma unroll
    for (int rr = 0; rr < 16; ++rr) {
      int h = (rr & 3) + 8 * (rr >> 2) + 4 * lg;
      po[h * 128 + dc * 32 + l31] = D[rr];
    }
  }
}

extern "C" void kernel_launch(void* const* d_in, const int* in_sizes, int n_in,
                              void* d_out, int out_size, void* d_ws, size_t ws_size,
                              hipStream_t stream) {
  const float* hs = (const float*)d_in[0];
  const float* wq = (const float*)d_in[1];
  const float* bq = (const float*)d_in[2];
  const float* wk = (const float*)d_in[3];
  const float* bk = (const float*)d_in[4];
  const float* wv = (const float*)d_in[5];
  const float* bv = (const float*)d_in[6];
  // wl/bl latent projection: unused by output — skipped.

  char* ws = (char*)d_ws;
  const size_t HS_OFF = 0;                    // 64 MiB
  const size_t W_OFF = 67108864;              // 96 MiB
  const size_t QKV_OFF = 167772160;           // 192 MiB
  const size_t BIAS_OFF = 369098752;          // 48 KiB
  const size_t NEED = 369147904;
  if (ws_size < NEED) return;

  unsigned short* hsb = (unsigned short*)(ws + HS_OFF);
  unsigned short* wb = (unsigned short*)(ws + W_OFF);
  unsigned short* qkv = (unsigned short*)(ws + QKV_OFF);
  float* bias = (float*)(ws + BIAS_OFF);

  cvt_fused<<<41008, 256, 0, stream>>>(hs, wq, wk, wv, bq, bk, bv, hsb, wb, bias);
  gemm_qkv<<<1536, 512, 0, stream>>>(hsb, wb, bias, qkv);   // 8 XCD x 4 tm x 48 tn
  attn_mfma<<<2048, 256, 0, stream>>>(qkv, (float*)d_out);  // 4 tokens/block
}